// Round 6
// baseline (270.787 us; speedup 1.0000x reference)
//
#include <hip/hip_runtime.h>
#include <hip/hip_bf16.h>
#include <math.h>

// Problem constants
#define T_LEN 2048
#define BSZ   2
#define EMB   1024
#define NH    16
#define HD    64
#define BHN   (BSZ*NH)      // 32
#define M1    (T_LEN*BSZ)   // 4096 rows of the projection GEMMs
#define SCAL  0.125f        // HD^-0.5
#define QSCALE (0.125f * 1.44269504088896f)   // SCAL * log2(e): softmax uses exp2

typedef __attribute__((ext_vector_type(8))) short bf16x8;   // 8 bf16 = 4 VGPRs
typedef __attribute__((ext_vector_type(4))) float f32x4;

__device__ inline unsigned short f2bf(float x) {
    union { float f; unsigned u; } v; v.f = x;
    unsigned r = v.u + 0x7FFF + ((v.u >> 16) & 1);   // RNE
    return (unsigned short)(r >> 16);
}

// packed f32x2 -> bf16x2 (v_cvt_pk_bf16_f32 on gfx950)
__device__ inline unsigned pack2bf(float a, float b) {
    union { __hip_bfloat162 h; unsigned u; } v;
    v.h = __float22bfloat162_rn(make_float2(a, b));
    return v.u;
}

__device__ inline float fexp2(float x) {
#if __has_builtin(__builtin_amdgcn_exp2f)
    return __builtin_amdgcn_exp2f(x);
#else
    return exp2f(x);
#endif
}

// async global->LDS, 16B per lane (wave-uniform LDS base + lane*16)
__device__ inline void async16(const unsigned short* g, unsigned short* l) {
    __builtin_amdgcn_global_load_lds(
        (const __attribute__((address_space(1))) void*)g,
        (__attribute__((address_space(3))) void*)l, 16, 0, 0);
}

// XOR-swizzled LDS address for an N-row x 8-chunk (16B) tile.
// LDS chunk = r*8 + (c ^ (r&7)); returns pointer in shorts.
__device__ inline unsigned short* swz(unsigned short* base, int r, int c) {
    return base + (((r << 3) + (c ^ (r & 7))) << 3);
}
__device__ inline const unsigned short* swz(const unsigned short* base, int r, int c) {
    return base + (((r << 3) + (c ^ (r & 7))) << 3);
}

// ---------------------------------------------------------------------------
// Kernel 0: fp32 -> bf16 elementwise convert (8 elems/thread, 16B stores)
// ---------------------------------------------------------------------------
__global__ __launch_bounds__(256) void cvt_bf16_kernel(
    const float* __restrict__ src, unsigned short* __restrict__ dst, int n8)
{
    int idx = blockIdx.x * 256 + threadIdx.x;
    if (idx >= n8) return;
    float4 a = reinterpret_cast<const float4*>(src)[idx * 2];
    float4 b = reinterpret_cast<const float4*>(src)[idx * 2 + 1];
    unsigned o[4] = { pack2bf(a.x, a.y), pack2bf(a.z, a.w),
                      pack2bf(b.x, b.y), pack2bf(b.z, b.w) };
    reinterpret_cast<uint4*>(dst)[idx] = *reinterpret_cast<uint4*>(o);
}

// ---------------------------------------------------------------------------
// Kernel 1: QKV projection, bf16 MFMA (m97 structure).
// Q16 is pre-scaled by SCAL*log2(e) so attention softmax can use raw exp2.
// ---------------------------------------------------------------------------
__global__ __launch_bounds__(256) void qkv_mfma_kernel(
    const unsigned short* __restrict__ A, const unsigned short* __restrict__ B,
    const float* __restrict__ bias,
    unsigned short* __restrict__ Q16, unsigned short* __restrict__ K16,
    unsigned short* __restrict__ Vt16)
{
    constexpr int BM = 128, BN = 128, BK = 32, K = 1024;
    __shared__ unsigned short As[BM * BK];   // contiguous, no pad (global_load_lds)
    __shared__ unsigned short Bs[BN * BK];
    const int tid = threadIdx.x;
    const int lane = tid & 63, wave = tid >> 6;
    const int quad = lane >> 4, l16 = lane & 15;
    const int wr = wave >> 1, wc = wave & 1;
    const int m0 = blockIdx.x * BM, n0 = blockIdx.y * BN;

    f32x4 zero4 = {0.f, 0.f, 0.f, 0.f};
    f32x4 acc[4][4];
    #pragma unroll
    for (int i = 0; i < 4; ++i)
        #pragma unroll
        for (int j = 0; j < 4; ++j) acc[i][j] = zero4;

    for (int k0 = 0; k0 < K; k0 += BK) {
        __syncthreads();
        #pragma unroll
        for (int t = 0; t < 2; ++t) {
            int c = t * 256 + tid;           // 16B chunk id, 0..511
            int m = c >> 2, kb = c & 3;
            async16(&A[(size_t)(m0 + m) * K + k0 + kb * 8], &As[c * 8]);
            async16(&B[(size_t)(n0 + m) * K + k0 + kb * 8], &Bs[c * 8]);
        }
        __syncthreads();
        bf16x8 af[4], bfr[4];
        #pragma unroll
        for (int i = 0; i < 4; ++i) {
            af[i]  = *reinterpret_cast<const bf16x8*>(&As[(wr * 64 + i * 16 + l16) * BK + quad * 8]);
            bfr[i] = *reinterpret_cast<const bf16x8*>(&Bs[(wc * 64 + i * 16 + l16) * BK + quad * 8]);
        }
        #pragma unroll
        for (int i = 0; i < 4; ++i)
            #pragma unroll
            for (int j = 0; j < 4; ++j)
                acc[i][j] = __builtin_amdgcn_mfma_f32_16x16x32_bf16(af[i], bfr[j], acc[i][j], 0, 0, 0);
    }

    // epilogue: bias + scatter (which/h uniform within each 16-col group)
    #pragma unroll
    for (int j = 0; j < 4; ++j) {
        int n = n0 + wc * 64 + j * 16 + l16;
        float bv = bias[n];
        int which = n >> 10;
        int c = n & 1023;
        int h = c >> 6, d = c & 63;
        #pragma unroll
        for (int i = 0; i < 4; ++i) {
            #pragma unroll
            for (int r = 0; r < 4; ++r) {
                int m = m0 + wr * 64 + i * 16 + quad * 4 + r;
                int t = m >> 1, b = m & 1;
                int bh = b * NH + h;
                float v = acc[i][j][r] + bv;
                if (which == 0)      Q16[((size_t)bh * T_LEN + t) * HD + d] = f2bf(v * QSCALE);
                else if (which == 1) K16[((size_t)bh * T_LEN + t) * HD + d] = f2bf(v);
                else                 Vt16[((size_t)bh * HD + d) * T_LEN + t] = f2bf(v);
            }
        }
    }
}

// ---------------------------------------------------------------------------
// Kernel 2: flash attention, bf16 MFMA, S^T formulation, no online max,
// BQ=128: each of 4 waves owns 32 q-rows (2 subtiles of 16). Every K/V
// fragment read from LDS feeds TWO MFMAs (one per q-subtile) -> LDS-read
// traffic per FLOP halves vs BQ=64; K/V staging per q also halves.
// Lrow stores the RECIPROCAL of the softmax denominator.
// ---------------------------------------------------------------------------
__global__ __launch_bounds__(256) void flash_mfma_kernel(
    const unsigned short* __restrict__ Qb, const unsigned short* __restrict__ Kb,
    const unsigned short* __restrict__ Vt, unsigned short* __restrict__ AO,
    float* __restrict__ Lrow)
{
    __shared__ unsigned short Ks[64 * 64];    // [key][d], swizzled chunks
    __shared__ unsigned short Vs[64 * 64];    // [d][key], swizzled chunks
    __shared__ unsigned short Ps[128 * 64];   // [q (block-local)][key], swizzled
    const int tid = threadIdx.x;
    const int lane = tid & 63, wave = tid >> 6;
    const int quad = lane >> 4, l16 = lane & 15;
    const int qt = blockIdx.x, bh = blockIdx.y;
    const int q0 = qt * 128;
    const int b = bh >> 4, h = bh & 15;

    // Q fragments for the 2 q-subtiles (B-operand of K·Q^T)
    bf16x8 qf[2][2];
    #pragma unroll
    for (int s = 0; s < 2; ++s) {
        const unsigned short* Qp =
            Qb + ((size_t)bh * T_LEN + q0 + wave * 32 + s * 16 + l16) * HD;
        qf[s][0] = *reinterpret_cast<const bf16x8*>(Qp + quad * 8);
        qf[s][1] = *reinterpret_cast<const bf16x8*>(Qp + 32 + quad * 8);
    }

    f32x4 zero4 = {0.f, 0.f, 0.f, 0.f};
    f32x4 oacc[4][2];   // O^T: [d-tile][q-sub], col q = l16
    #pragma unroll
    for (int dt = 0; dt < 4; ++dt) { oacc[dt][0] = zero4; oacc[dt][1] = zero4; }
    float l_i[2] = {0.f, 0.f};

    const unsigned short* Kbase = Kb + (size_t)bh * T_LEN * HD;
    const unsigned short* Vbase = Vt + (size_t)bh * HD * T_LEN;

    // staging indices (swizzle: lds chunk cl -> row r, data chunk c)
    const int cl0 = tid, cl1 = tid + 256;
    const int r0 = cl0 >> 3, c0 = (cl0 & 7) ^ (r0 & 7);
    const int r1 = cl1 >> 3, c1 = (cl1 & 7) ^ (r1 & 7);

    for (int kt = 0; kt < T_LEN; kt += 64) {
        __syncthreads();
        async16(&Kbase[(size_t)(kt + r0) * HD + c0 * 8], &Ks[cl0 * 8]);
        async16(&Kbase[(size_t)(kt + r1) * HD + c1 * 8], &Ks[cl1 * 8]);
        async16(&Vbase[(size_t)r0 * T_LEN + kt + c0 * 8], &Vs[cl0 * 8]);
        async16(&Vbase[(size_t)r1 * T_LEN + kt + c1 * 8], &Vs[cl1 * 8]);
        __syncthreads();

        // S^T = K Q^T : lane holds rows key = kb*16+quad*4+r, col q = l16
        // (per subtile). Each kf read feeds both q-subtiles.
        f32x4 sacc[2][4];
        #pragma unroll
        for (int kb = 0; kb < 4; ++kb) { sacc[0][kb] = zero4; sacc[1][kb] = zero4; }
        #pragma unroll
        for (int kb = 0; kb < 4; ++kb) {
            bf16x8 kf0 = *reinterpret_cast<const bf16x8*>(swz(Ks, kb * 16 + l16, quad));
            sacc[0][kb] = __builtin_amdgcn_mfma_f32_16x16x32_bf16(kf0, qf[0][0], sacc[0][kb], 0, 0, 0);
            sacc[1][kb] = __builtin_amdgcn_mfma_f32_16x16x32_bf16(kf0, qf[1][0], sacc[1][kb], 0, 0, 0);
            bf16x8 kf1 = *reinterpret_cast<const bf16x8*>(swz(Ks, kb * 16 + l16, 4 + quad));
            sacc[0][kb] = __builtin_amdgcn_mfma_f32_16x16x32_bf16(kf1, qf[0][1], sacc[0][kb], 0, 0, 0);
            sacc[1][kb] = __builtin_amdgcn_mfma_f32_16x16x32_bf16(kf1, qf[1][1], sacc[1][kb], 0, 0, 0);
        }

        // p = exp2(s), accumulate denominator; store P (bf16, packed cvt)
        #pragma unroll
        for (int s = 0; s < 2; ++s) {
            const int Rp = wave * 32 + s * 16 + l16;
            float psum = 0.f;
            #pragma unroll
            for (int kb = 0; kb < 4; ++kb) {
                float p0 = fexp2(sacc[s][kb][0]);
                float p1 = fexp2(sacc[s][kb][1]);
                float p2 = fexp2(sacc[s][kb][2]);
                float p3 = fexp2(sacc[s][kb][3]);
                psum += (p0 + p1) + (p2 + p3);
                unsigned o[2] = { pack2bf(p0, p1), pack2bf(p2, p3) };
                *reinterpret_cast<uint2*>(
                    swz(Ps, Rp, 2 * kb + (quad >> 1)) + (quad & 1) * 4) =
                    *reinterpret_cast<uint2*>(o);
            }
            psum += __shfl_xor(psum, 16);
            psum += __shfl_xor(psum, 32);
            l_i[s] += psum;
        }
        // Ps strips are wave-local (written & read by the same wave, in order).

        // O^T += V^T P^T : each va read feeds both q-subtiles.
        #pragma unroll
        for (int st = 0; st < 2; ++st) {
            bf16x8 pb0 = *reinterpret_cast<const bf16x8*>(swz(Ps, wave * 32 + l16, st * 4 + quad));
            bf16x8 pb1 = *reinterpret_cast<const bf16x8*>(swz(Ps, wave * 32 + 16 + l16, st * 4 + quad));
            #pragma unroll
            for (int dt = 0; dt < 4; ++dt) {
                bf16x8 va = *reinterpret_cast<const bf16x8*>(swz(Vs, dt * 16 + l16, st * 4 + quad));
                oacc[dt][0] = __builtin_amdgcn_mfma_f32_16x16x32_bf16(va, pb0, oacc[dt][0], 0, 0, 0);
                oacc[dt][1] = __builtin_amdgcn_mfma_f32_16x16x32_bf16(va, pb1, oacc[dt][1], 0, 0, 0);
            }
        }
    }

    // epilogue: per subtile, lane owns q = q0 + wave*32 + s*16 + l16.
    #pragma unroll
    for (int s = 0; s < 2; ++s) {
        float rl = 1.0f / l_i[s];
        int q = q0 + wave * 32 + s * 16 + l16;
        size_t base = ((size_t)q * BSZ + b) * EMB + h * HD;
        #pragma unroll
        for (int dt = 0; dt < 4; ++dt) {
            unsigned o[2] = { pack2bf(oacc[dt][0][s ? 0 : 0] * 0.f + oacc[dt][s][0] * rl,
                                      oacc[dt][s][1] * rl),
                              pack2bf(oacc[dt][s][2] * rl, oacc[dt][s][3] * rl) };
            *reinterpret_cast<uint2*>(&AO[base + dt * 16 + quad * 4]) = *reinterpret_cast<uint2*>(o);
        }
        if (quad == 0)
            Lrow[(size_t)bh * T_LEN + q] = rl;   // reciprocal for avg kernel
    }
}

// ---------------------------------------------------------------------------
// Kernel 3: averaged attention weights, bf16 MFMA, no max (exp2 units).
// Lrow holds reciprocal denominators (multiply, no divide).
// ---------------------------------------------------------------------------
__global__ __launch_bounds__(256) void avg_mfma_kernel(
    const unsigned short* __restrict__ Qb, const unsigned short* __restrict__ Kb,
    const float* __restrict__ Lrow, float* __restrict__ avg_out)
{
    __shared__ unsigned short Ks[64 * 64];   // swizzled chunks
    const int tid = threadIdx.x;
    const int lane = tid & 63, wave = tid >> 6;
    const int quad = lane >> 4, l16 = lane & 15;
    const int kt = blockIdx.x, qt = blockIdx.y, b = blockIdx.z;
    const int q0 = qt * 64, k0 = kt * 64;

    const int cl0 = tid, cl1 = tid + 256;
    const int r0 = cl0 >> 3, c0 = (cl0 & 7) ^ (r0 & 7);
    const int r1 = cl1 >> 3, c1 = (cl1 & 7) ^ (r1 & 7);

    f32x4 zero4 = {0.f, 0.f, 0.f, 0.f};
    f32x4 acc[4] = {zero4, zero4, zero4, zero4};

    for (int h = 0; h < NH; ++h) {
        int bh = b * NH + h;
        __syncthreads();
        const unsigned short* Kg = Kb + ((size_t)bh * T_LEN + k0) * HD;
        async16(&Kg[(size_t)r0 * HD + c0 * 8], &Ks[cl0 * 8]);
        async16(&Kg[(size_t)r1 * HD + c1 * 8], &Ks[cl1 * 8]);
        __syncthreads();

        const unsigned short* Qp = Qb + ((size_t)bh * T_LEN + q0 + wave * 16 + l16) * HD;
        bf16x8 qf0 = *reinterpret_cast<const bf16x8*>(Qp + quad * 8);
        bf16x8 qf1 = *reinterpret_cast<const bf16x8*>(Qp + 32 + quad * 8);

        // S tile: lane holds rows q = wave*16+quad*4+r, col key = c*16+l16
        f32x4 sacc[4] = {zero4, zero4, zero4, zero4};
        #pragma unroll
        for (int c = 0; c < 4; ++c) {
            bf16x8 kb0 = *reinterpret_cast<const bf16x8*>(swz(Ks, c * 16 + l16, quad));
            sacc[c] = __builtin_amdgcn_mfma_f32_16x16x32_bf16(qf0, kb0, sacc[c], 0, 0, 0);
            bf16x8 kb1 = *reinterpret_cast<const bf16x8*>(swz(Ks, c * 16 + l16, 4 + quad));
            sacc[c] = __builtin_amdgcn_mfma_f32_16x16x32_bf16(qf1, kb1, sacc[c], 0, 0, 0);
        }
        #pragma unroll
        for (int r = 0; r < 4; ++r) {
            int q = q0 + wave * 16 + quad * 4 + r;
            float rl = Lrow[(size_t)bh * T_LEN + q];
            #pragma unroll
            for (int c = 0; c < 4; ++c)
                acc[c][r] += fexp2(sacc[c][r]) * rl;
        }
    }
    #pragma unroll
    for (int r = 0; r < 4; ++r) {
        int q = q0 + wave * 16 + quad * 4 + r;
        size_t base = ((size_t)b * T_LEN + q) * T_LEN + k0;
        #pragma unroll
        for (int c = 0; c < 4; ++c)
            avg_out[base + c * 16 + l16] = acc[c][r] * (1.0f / 16.0f);
    }
}

// ---------------------------------------------------------------------------
// Kernel 4: output projection, bf16 MFMA. out = AO @ out_w^T + out_b (fp32 out)
// ---------------------------------------------------------------------------
__global__ __launch_bounds__(256) void out_mfma_kernel(
    const unsigned short* __restrict__ A, const unsigned short* __restrict__ B,
    const float* __restrict__ bias, float* __restrict__ out)
{
    constexpr int BM = 128, BN = 128, BK = 32, K = 1024;
    __shared__ unsigned short As[BM * BK];
    __shared__ unsigned short Bs[BN * BK];
    const int tid = threadIdx.x;
    const int lane = tid & 63, wave = tid >> 6;
    const int quad = lane >> 4, l16 = lane & 15;
    const int wr = wave >> 1, wc = wave & 1;
    const int m0 = blockIdx.x * BM, n0 = blockIdx.y * BN;

    f32x4 zero4 = {0.f, 0.f, 0.f, 0.f};
    f32x4 acc[4][4];
    #pragma unroll
    for (int i = 0; i < 4; ++i)
        #pragma unroll
        for (int j = 0; j < 4; ++j) acc[i][j] = zero4;

    for (int k0 = 0; k0 < K; k0 += BK) {
        __syncthreads();
        #pragma unroll
        for (int t = 0; t < 2; ++t) {
            int c = t * 256 + tid;
            int m = c >> 2, kb = c & 3;
            async16(&A[(size_t)(m0 + m) * K + k0 + kb * 8], &As[c * 8]);
            async16(&B[(size_t)(n0 + m) * K + k0 + kb * 8], &Bs[c * 8]);
        }
        __syncthreads();
        bf16x8 af[4], bfr[4];
        #pragma unroll
        for (int i = 0; i < 4; ++i) {
            af[i]  = *reinterpret_cast<const bf16x8*>(&As[(wr * 64 + i * 16 + l16) * BK + quad * 8]);
            bfr[i] = *reinterpret_cast<const bf16x8*>(&Bs[(wc * 64 + i * 16 + l16) * BK + quad * 8]);
        }
        #pragma unroll
        for (int i = 0; i < 4; ++i)
            #pragma unroll
            for (int j = 0; j < 4; ++j)
                acc[i][j] = __builtin_amdgcn_mfma_f32_16x16x32_bf16(af[i], bfr[j], acc[i][j], 0, 0, 0);
    }

    #pragma unroll
    for (int j = 0; j < 4; ++j) {
        int n = n0 + wc * 64 + j * 16 + l16;
        float bv = bias[n];
        #pragma unroll
        for (int i = 0; i < 4; ++i) {
            #pragma unroll
            for (int r = 0; r < 4; ++r) {
                int m = m0 + wr * 64 + i * 16 + quad * 4 + r;
                out[(size_t)m * 1024 + n] = acc[i][j][r] + bv;
            }
        }
    }
}

// ---------------------------------------------------------------------------
extern "C" void kernel_launch(void* const* d_in, const int* in_sizes, int n_in,
                              void* d_out, int out_size, void* d_ws, size_t ws_size,
                              hipStream_t stream)
{
    const float* query = (const float*)d_in[0];   // [2048][2][1024]
    const float* wqkv  = (const float*)d_in[1];   // [3072][1024]
    const float* bqkv  = (const float*)d_in[2];   // [3072]
    const float* wout  = (const float*)d_in[3];   // [1024][1024]
    const float* bout  = (const float*)d_in[4];   // [1024]
    float* out = (float*)d_out;                   // [4096*1024] attn ++ [2*2048*2048] avg

    char* ws = (char*)d_ws;
    const size_t E_Q   = (size_t)M1 * EMB;        // 4M
    const size_t E_W   = (size_t)3 * EMB * EMB;   // 3M
    const size_t E_WO  = (size_t)EMB * EMB;       // 1M
    const size_t E_QKV = (size_t)BHN * T_LEN * HD;// 4M

    unsigned short* queryb = (unsigned short*)ws;                 // 8 MB
    unsigned short* wqkvb  = queryb + E_Q;                        // 6 MB
    unsigned short* woutb  = wqkvb + E_W;                         // 2 MB
    unsigned short* Q16    = woutb + E_WO;                        // 8 MB
    unsigned short* K16    = Q16 + E_QKV;                         // 8 MB
    unsigned short* Vt16   = K16 + E_QKV;                         // 8 MB
    unsigned short* AO16   = Vt16 + E_QKV;                        // 8 MB
    float* Lr = (float*)(AO16 + E_Q);
    const size_t need = (E_Q + E_W + E_WO + 4 * E_QKV) * 2 + (size_t)BHN * T_LEN * 4;
    if (ws_size < need) return;

    cvt_bf16_kernel<<<(int)(E_Q / 8 / 256), 256, 0, stream>>>(query, queryb, (int)(E_Q / 8));
    cvt_bf16_kernel<<<(int)(E_W / 8 / 256), 256, 0, stream>>>(wqkv, wqkvb, (int)(E_W / 8));
    cvt_bf16_kernel<<<(int)(E_WO / 8 / 256), 256, 0, stream>>>(wout, woutb, (int)(E_WO / 8));

    qkv_mfma_kernel<<<dim3(M1 / 128, 3072 / 128), 256, 0, stream>>>(queryb, wqkvb, bqkv, Q16, K16, Vt16);
    flash_mfma_kernel<<<dim3(T_LEN / 128, BHN), 256, 0, stream>>>(Q16, K16, Vt16, AO16, Lr);
    avg_mfma_kernel<<<dim3(T_LEN / 64, T_LEN / 64, BSZ), 256, 0, stream>>>(Q16, K16, Lr, out + (size_t)M1 * EMB);
    out_mfma_kernel<<<dim3(M1 / 128, 1024 / 128), 256, 0, stream>>>(AO16, woutb, bout, out);
}

// Round 7
// 261.558 us; speedup vs baseline: 1.0353x; 1.0353x over previous
//
#include <hip/hip_runtime.h>
#include <hip/hip_bf16.h>
#include <math.h>

// Problem constants
#define T_LEN 2048
#define BSZ   2
#define EMB   1024
#define NH    16
#define HD    64
#define BHN   (BSZ*NH)      // 32
#define M1    (T_LEN*BSZ)   // 4096 rows of the projection GEMMs
#define SCAL  0.125f        // HD^-0.5
#define QSCALE (0.125f * 1.44269504088896f)   // SCAL * log2(e): softmax uses exp2
#define KSPLIT 2

typedef __attribute__((ext_vector_type(8))) short bf16x8;   // 8 bf16 = 4 VGPRs
typedef __attribute__((ext_vector_type(4))) float f32x4;

__device__ inline unsigned short f2bf(float x) {
    union { float f; unsigned u; } v; v.f = x;
    unsigned r = v.u + 0x7FFF + ((v.u >> 16) & 1);   // RNE
    return (unsigned short)(r >> 16);
}

__device__ inline float bf2f(unsigned short x) {
    union { unsigned u; float f; } v; v.u = ((unsigned)x) << 16;
    return v.f;
}

// packed f32x2 -> bf16x2 (v_cvt_pk_bf16_f32 on gfx950)
__device__ inline unsigned pack2bf(float a, float b) {
    union { __hip_bfloat162 h; unsigned u; } v;
    v.h = __float22bfloat162_rn(make_float2(a, b));
    return v.u;
}

__device__ inline float fexp2(float x) {
#if __has_builtin(__builtin_amdgcn_exp2f)
    return __builtin_amdgcn_exp2f(x);
#else
    return exp2f(x);
#endif
}

// async global->LDS, 16B per lane (wave-uniform LDS base + lane*16)
__device__ inline void async16(const unsigned short* g, unsigned short* l) {
    __builtin_amdgcn_global_load_lds(
        (const __attribute__((address_space(1))) void*)g,
        (__attribute__((address_space(3))) void*)l, 16, 0, 0);
}

// XOR-swizzled LDS address for an N-row x 8-chunk (16B) tile.
// LDS chunk = r*8 + (c ^ (r&7)); returns pointer in shorts.
__device__ inline unsigned short* swz(unsigned short* base, int r, int c) {
    return base + (((r << 3) + (c ^ (r & 7))) << 3);
}
__device__ inline const unsigned short* swz(const unsigned short* base, int r, int c) {
    return base + (((r << 3) + (c ^ (r & 7))) << 3);
}

// ---------------------------------------------------------------------------
// Kernel 0: fp32 -> bf16 elementwise convert (8 elems/thread, 16B stores)
// ---------------------------------------------------------------------------
__global__ __launch_bounds__(256) void cvt_bf16_kernel(
    const float* __restrict__ src, unsigned short* __restrict__ dst, int n8)
{
    int idx = blockIdx.x * 256 + threadIdx.x;
    if (idx >= n8) return;
    float4 a = reinterpret_cast<const float4*>(src)[idx * 2];
    float4 b = reinterpret_cast<const float4*>(src)[idx * 2 + 1];
    unsigned o[4] = { pack2bf(a.x, a.y), pack2bf(a.z, a.w),
                      pack2bf(b.x, b.y), pack2bf(b.z, b.w) };
    reinterpret_cast<uint4*>(dst)[idx] = *reinterpret_cast<uint4*>(o);
}

// ---------------------------------------------------------------------------
// Kernel 1: QKV projection, bf16 MFMA (m97 structure).
// Q16 is pre-scaled by SCAL*log2(e) so attention softmax can use raw exp2.
// ---------------------------------------------------------------------------
__global__ __launch_bounds__(256) void qkv_mfma_kernel(
    const unsigned short* __restrict__ A, const unsigned short* __restrict__ B,
    const float* __restrict__ bias,
    unsigned short* __restrict__ Q16, unsigned short* __restrict__ K16,
    unsigned short* __restrict__ Vt16)
{
    constexpr int BM = 128, BN = 128, BK = 32, K = 1024;
    __shared__ unsigned short As[BM * BK];   // contiguous, no pad (global_load_lds)
    __shared__ unsigned short Bs[BN * BK];
    const int tid = threadIdx.x;
    const int lane = tid & 63, wave = tid >> 6;
    const int quad = lane >> 4, l16 = lane & 15;
    const int wr = wave >> 1, wc = wave & 1;
    const int m0 = blockIdx.x * BM, n0 = blockIdx.y * BN;

    f32x4 zero4 = {0.f, 0.f, 0.f, 0.f};
    f32x4 acc[4][4];
    #pragma unroll
    for (int i = 0; i < 4; ++i)
        #pragma unroll
        for (int j = 0; j < 4; ++j) acc[i][j] = zero4;

    for (int k0 = 0; k0 < K; k0 += BK) {
        __syncthreads();
        #pragma unroll
        for (int t = 0; t < 2; ++t) {
            int c = t * 256 + tid;           // 16B chunk id, 0..511
            int m = c >> 2, kb = c & 3;
            async16(&A[(size_t)(m0 + m) * K + k0 + kb * 8], &As[c * 8]);
            async16(&B[(size_t)(n0 + m) * K + k0 + kb * 8], &Bs[c * 8]);
        }
        __syncthreads();
        bf16x8 af[4], bfr[4];
        #pragma unroll
        for (int i = 0; i < 4; ++i) {
            af[i]  = *reinterpret_cast<const bf16x8*>(&As[(wr * 64 + i * 16 + l16) * BK + quad * 8]);
            bfr[i] = *reinterpret_cast<const bf16x8*>(&Bs[(wc * 64 + i * 16 + l16) * BK + quad * 8]);
        }
        #pragma unroll
        for (int i = 0; i < 4; ++i)
            #pragma unroll
            for (int j = 0; j < 4; ++j)
                acc[i][j] = __builtin_amdgcn_mfma_f32_16x16x32_bf16(af[i], bfr[j], acc[i][j], 0, 0, 0);
    }

    // epilogue: bias + scatter (which/h uniform within each 16-col group)
    #pragma unroll
    for (int j = 0; j < 4; ++j) {
        int n = n0 + wc * 64 + j * 16 + l16;
        float bv = bias[n];
        int which = n >> 10;
        int c = n & 1023;
        int h = c >> 6, d = c & 63;
        #pragma unroll
        for (int i = 0; i < 4; ++i) {
            #pragma unroll
            for (int r = 0; r < 4; ++r) {
                int m = m0 + wr * 64 + i * 16 + quad * 4 + r;
                int t = m >> 1, b = m & 1;
                int bh = b * NH + h;
                float v = acc[i][j][r] + bv;
                if (which == 0)      Q16[((size_t)bh * T_LEN + t) * HD + d] = f2bf(v * QSCALE);
                else if (which == 1) K16[((size_t)bh * T_LEN + t) * HD + d] = f2bf(v);
                else                 Vt16[((size_t)bh * HD + d) * T_LEN + t] = f2bf(v);
            }
        }
    }
}

// ---------------------------------------------------------------------------
// Kernel 2: flash attention, bf16 MFMA, S^T formulation, no online max,
// BQ=128 (K/V fragment reuse across 2 q-subtiles) + KSPLIT=2 along keys
// (blockIdx.z) to restore 4 blocks/CU. Since softmax has no running max,
// K-split partials combine additively: this kernel writes UNNORMALIZED
// bf16 O-partials [ks][t][b][e] and partial denominators Lpart[ks][bh][t].
// ---------------------------------------------------------------------------
__global__ __launch_bounds__(256) void flash_mfma_kernel(
    const unsigned short* __restrict__ Qb, const unsigned short* __restrict__ Kb,
    const unsigned short* __restrict__ Vt, unsigned short* __restrict__ Opart,
    float* __restrict__ Lpart)
{
    __shared__ unsigned short Ks[64 * 64];    // [key][d], swizzled chunks
    __shared__ unsigned short Vs[64 * 64];    // [d][key], swizzled chunks
    __shared__ unsigned short Ps[128 * 64];   // [q (block-local)][key], swizzled
    const int tid = threadIdx.x;
    const int lane = tid & 63, wave = tid >> 6;
    const int quad = lane >> 4, l16 = lane & 15;
    const int qt = blockIdx.x, bh = blockIdx.y, ks = blockIdx.z;
    const int q0 = qt * 128;
    const int b = bh >> 4, h = bh & 15;
    const int kt0 = ks * (T_LEN / KSPLIT), kt1 = kt0 + T_LEN / KSPLIT;

    // Q fragments for the 2 q-subtiles (B-operand of K·Q^T)
    bf16x8 qf[2][2];
    #pragma unroll
    for (int s = 0; s < 2; ++s) {
        const unsigned short* Qp =
            Qb + ((size_t)bh * T_LEN + q0 + wave * 32 + s * 16 + l16) * HD;
        qf[s][0] = *reinterpret_cast<const bf16x8*>(Qp + quad * 8);
        qf[s][1] = *reinterpret_cast<const bf16x8*>(Qp + 32 + quad * 8);
    }

    f32x4 zero4 = {0.f, 0.f, 0.f, 0.f};
    f32x4 oacc[4][2];   // O^T: [d-tile][q-sub], col q = l16
    #pragma unroll
    for (int dt = 0; dt < 4; ++dt) { oacc[dt][0] = zero4; oacc[dt][1] = zero4; }
    float l_i[2] = {0.f, 0.f};

    const unsigned short* Kbase = Kb + (size_t)bh * T_LEN * HD;
    const unsigned short* Vbase = Vt + (size_t)bh * HD * T_LEN;

    // staging indices (swizzle: lds chunk cl -> row r, data chunk c)
    const int cl0 = tid, cl1 = tid + 256;
    const int r0 = cl0 >> 3, c0 = (cl0 & 7) ^ (r0 & 7);
    const int r1 = cl1 >> 3, c1 = (cl1 & 7) ^ (r1 & 7);

    for (int kt = kt0; kt < kt1; kt += 64) {
        __syncthreads();
        async16(&Kbase[(size_t)(kt + r0) * HD + c0 * 8], &Ks[cl0 * 8]);
        async16(&Kbase[(size_t)(kt + r1) * HD + c1 * 8], &Ks[cl1 * 8]);
        async16(&Vbase[(size_t)r0 * T_LEN + kt + c0 * 8], &Vs[cl0 * 8]);
        async16(&Vbase[(size_t)r1 * T_LEN + kt + c1 * 8], &Vs[cl1 * 8]);
        __syncthreads();

        // S^T = K Q^T : lane holds rows key = kb*16+quad*4+r, col q = l16
        // (per subtile). Each kf read feeds both q-subtiles.
        f32x4 sacc[2][4];
        #pragma unroll
        for (int kb = 0; kb < 4; ++kb) { sacc[0][kb] = zero4; sacc[1][kb] = zero4; }
        #pragma unroll
        for (int kb = 0; kb < 4; ++kb) {
            bf16x8 kf0 = *reinterpret_cast<const bf16x8*>(swz(Ks, kb * 16 + l16, quad));
            sacc[0][kb] = __builtin_amdgcn_mfma_f32_16x16x32_bf16(kf0, qf[0][0], sacc[0][kb], 0, 0, 0);
            sacc[1][kb] = __builtin_amdgcn_mfma_f32_16x16x32_bf16(kf0, qf[1][0], sacc[1][kb], 0, 0, 0);
            bf16x8 kf1 = *reinterpret_cast<const bf16x8*>(swz(Ks, kb * 16 + l16, 4 + quad));
            sacc[0][kb] = __builtin_amdgcn_mfma_f32_16x16x32_bf16(kf1, qf[0][1], sacc[0][kb], 0, 0, 0);
            sacc[1][kb] = __builtin_amdgcn_mfma_f32_16x16x32_bf16(kf1, qf[1][1], sacc[1][kb], 0, 0, 0);
        }

        // p = exp2(s), accumulate denominator; store P (bf16, packed cvt)
        #pragma unroll
        for (int s = 0; s < 2; ++s) {
            const int Rp = wave * 32 + s * 16 + l16;
            float psum = 0.f;
            #pragma unroll
            for (int kb = 0; kb < 4; ++kb) {
                float p0 = fexp2(sacc[s][kb][0]);
                float p1 = fexp2(sacc[s][kb][1]);
                float p2 = fexp2(sacc[s][kb][2]);
                float p3 = fexp2(sacc[s][kb][3]);
                psum += (p0 + p1) + (p2 + p3);
                unsigned o[2] = { pack2bf(p0, p1), pack2bf(p2, p3) };
                *reinterpret_cast<uint2*>(
                    swz(Ps, Rp, 2 * kb + (quad >> 1)) + (quad & 1) * 4) =
                    *reinterpret_cast<uint2*>(o);
            }
            psum += __shfl_xor(psum, 16);
            psum += __shfl_xor(psum, 32);
            l_i[s] += psum;
        }
        // Ps strips are wave-local (written & read by the same wave, in order).

        // O^T += V^T P^T : each va read feeds both q-subtiles.
        #pragma unroll
        for (int st = 0; st < 2; ++st) {
            bf16x8 pb0 = *reinterpret_cast<const bf16x8*>(swz(Ps, wave * 32 + l16, st * 4 + quad));
            bf16x8 pb1 = *reinterpret_cast<const bf16x8*>(swz(Ps, wave * 32 + 16 + l16, st * 4 + quad));
            #pragma unroll
            for (int dt = 0; dt < 4; ++dt) {
                bf16x8 va = *reinterpret_cast<const bf16x8*>(swz(Vs, dt * 16 + l16, st * 4 + quad));
                oacc[dt][0] = __builtin_amdgcn_mfma_f32_16x16x32_bf16(va, pb0, oacc[dt][0], 0, 0, 0);
                oacc[dt][1] = __builtin_amdgcn_mfma_f32_16x16x32_bf16(va, pb1, oacc[dt][1], 0, 0, 0);
            }
        }
    }

    // epilogue: per subtile, lane owns q = q0 + wave*32 + s*16 + l16.
    // Store UNNORMALIZED partial O (bf16) + partial l.
    #pragma unroll
    for (int s = 0; s < 2; ++s) {
        int q = q0 + wave * 32 + s * 16 + l16;
        size_t base = (size_t)ks * M1 * EMB + ((size_t)q * BSZ + b) * EMB + h * HD;
        #pragma unroll
        for (int dt = 0; dt < 4; ++dt) {
            unsigned o[2] = { pack2bf(oacc[dt][s][0], oacc[dt][s][1]),
                              pack2bf(oacc[dt][s][2], oacc[dt][s][3]) };
            *reinterpret_cast<uint2*>(&Opart[base + dt * 16 + quad * 4]) =
                *reinterpret_cast<uint2*>(o);
        }
        if (quad == 0)
            Lpart[(size_t)ks * BHN * T_LEN + (size_t)bh * T_LEN + q] = l_i[s];
    }
}

// ---------------------------------------------------------------------------
// Kernel 2b: combine K-split partials. AO = (O0+O1)/(l0+l1), Lrec = 1/l.
// 8 elems/thread; one thread per (t,b,h) row writes Lrec.
// ---------------------------------------------------------------------------
__global__ __launch_bounds__(256) void combine_kernel(
    const unsigned short* __restrict__ Opart, const float* __restrict__ Lpart,
    unsigned short* __restrict__ AO, float* __restrict__ Lrec)
{
    int idx = blockIdx.x * 256 + threadIdx.x;      // 0 .. M1*EMB/8-1
    int e8 = idx * 8;
    int t = e8 >> 11;            // / (BSZ*EMB)
    int rem = e8 & 2047;
    int b = rem >> 10;
    int e = rem & 1023;
    int h = e >> 6;
    int bh = b * NH + h;
    size_t lidx = (size_t)bh * T_LEN + t;
    float l = Lpart[lidx] + Lpart[(size_t)BHN * T_LEN + lidx];
    float rl = 1.0f / l;
    uint4 pa = reinterpret_cast<const uint4*>(Opart)[idx];
    uint4 pb = reinterpret_cast<const uint4*>(Opart)[(size_t)M1 * EMB / 8 + idx];
    const unsigned short* sa = reinterpret_cast<const unsigned short*>(&pa);
    const unsigned short* sb = reinterpret_cast<const unsigned short*>(&pb);
    unsigned o[4];
    #pragma unroll
    for (int i = 0; i < 4; ++i) {
        float v0 = (bf2f(sa[2 * i])     + bf2f(sb[2 * i]))     * rl;
        float v1 = (bf2f(sa[2 * i + 1]) + bf2f(sb[2 * i + 1])) * rl;
        o[i] = pack2bf(v0, v1);
    }
    reinterpret_cast<uint4*>(AO)[idx] = *reinterpret_cast<uint4*>(o);
    if ((e & 63) == 0) Lrec[lidx] = rl;
}

// ---------------------------------------------------------------------------
// Kernel 3: averaged attention weights, bf16 MFMA, no max (exp2 units),
// double-buffered per-head K staging (prefetch issued after the barrier,
// drained at the NEXT barrier -> full compute phase in flight).
// Lrec holds reciprocal denominators (multiply, no divide).
// ---------------------------------------------------------------------------
__global__ __launch_bounds__(256) void avg_mfma_kernel(
    const unsigned short* __restrict__ Qb, const unsigned short* __restrict__ Kb,
    const float* __restrict__ Lrec, float* __restrict__ avg_out)
{
    __shared__ unsigned short Ks[2][64 * 64];   // swizzled chunks, double-buffered
    const int tid = threadIdx.x;
    const int lane = tid & 63, wave = tid >> 6;
    const int quad = lane >> 4, l16 = lane & 15;
    const int kt = blockIdx.x, qt = blockIdx.y, b = blockIdx.z;
    const int q0 = qt * 64, k0 = kt * 64;

    const int cl0 = tid, cl1 = tid + 256;
    const int r0 = cl0 >> 3, c0 = (cl0 & 7) ^ (r0 & 7);
    const int r1 = cl1 >> 3, c1 = (cl1 & 7) ^ (r1 & 7);

    f32x4 zero4 = {0.f, 0.f, 0.f, 0.f};
    f32x4 acc[4] = {zero4, zero4, zero4, zero4};

    // prologue: stage head 0 into buffer 0
    {
        const unsigned short* Kg = Kb + ((size_t)(b * NH) * T_LEN + k0) * HD;
        async16(&Kg[(size_t)r0 * HD + c0 * 8], &Ks[0][cl0 * 8]);
        async16(&Kg[(size_t)r1 * HD + c1 * 8], &Ks[0][cl1 * 8]);
    }

    for (int h = 0; h < NH; ++h) {
        int bh = b * NH + h;
        __syncthreads();   // drains vmcnt: Ks[h&1] ready; protects buffer reuse
        if (h + 1 < NH) {  // prefetch next head into the other buffer
            const unsigned short* Kg = Kb + ((size_t)(bh + 1) * T_LEN + k0) * HD;
            async16(&Kg[(size_t)r0 * HD + c0 * 8], &Ks[(h + 1) & 1][cl0 * 8]);
            async16(&Kg[(size_t)r1 * HD + c1 * 8], &Ks[(h + 1) & 1][cl1 * 8]);
        }
        const unsigned short* Kcur = Ks[h & 1];

        const unsigned short* Qp = Qb + ((size_t)bh * T_LEN + q0 + wave * 16 + l16) * HD;
        bf16x8 qf0 = *reinterpret_cast<const bf16x8*>(Qp + quad * 8);
        bf16x8 qf1 = *reinterpret_cast<const bf16x8*>(Qp + 32 + quad * 8);

        // S tile: lane holds rows q = wave*16+quad*4+r, col key = c*16+l16
        f32x4 sacc[4] = {zero4, zero4, zero4, zero4};
        #pragma unroll
        for (int c = 0; c < 4; ++c) {
            bf16x8 kb0 = *reinterpret_cast<const bf16x8*>(swz(Kcur, c * 16 + l16, quad));
            sacc[c] = __builtin_amdgcn_mfma_f32_16x16x32_bf16(qf0, kb0, sacc[c], 0, 0, 0);
            bf16x8 kb1 = *reinterpret_cast<const bf16x8*>(swz(Kcur, c * 16 + l16, 4 + quad));
            sacc[c] = __builtin_amdgcn_mfma_f32_16x16x32_bf16(qf1, kb1, sacc[c], 0, 0, 0);
        }
        #pragma unroll
        for (int r = 0; r < 4; ++r) {
            int q = q0 + wave * 16 + quad * 4 + r;
            float rl = Lrec[(size_t)bh * T_LEN + q];
            #pragma unroll
            for (int c = 0; c < 4; ++c)
                acc[c][r] += fexp2(sacc[c][r]) * rl;
        }
    }
    #pragma unroll
    for (int r = 0; r < 4; ++r) {
        int q = q0 + wave * 16 + quad * 4 + r;
        size_t base = ((size_t)b * T_LEN + q) * T_LEN + k0;
        #pragma unroll
        for (int c = 0; c < 4; ++c)
            avg_out[base + c * 16 + l16] = acc[c][r] * (1.0f / 16.0f);
    }
}

// ---------------------------------------------------------------------------
// Kernel 4: output projection, bf16 MFMA. out = AO @ out_w^T + out_b (fp32 out)
// ---------------------------------------------------------------------------
__global__ __launch_bounds__(256) void out_mfma_kernel(
    const unsigned short* __restrict__ A, const unsigned short* __restrict__ B,
    const float* __restrict__ bias, float* __restrict__ out)
{
    constexpr int BM = 128, BN = 128, BK = 32, K = 1024;
    __shared__ unsigned short As[BM * BK];
    __shared__ unsigned short Bs[BN * BK];
    const int tid = threadIdx.x;
    const int lane = tid & 63, wave = tid >> 6;
    const int quad = lane >> 4, l16 = lane & 15;
    const int wr = wave >> 1, wc = wave & 1;
    const int m0 = blockIdx.x * BM, n0 = blockIdx.y * BN;

    f32x4 zero4 = {0.f, 0.f, 0.f, 0.f};
    f32x4 acc[4][4];
    #pragma unroll
    for (int i = 0; i < 4; ++i)
        #pragma unroll
        for (int j = 0; j < 4; ++j) acc[i][j] = zero4;

    for (int k0 = 0; k0 < K; k0 += BK) {
        __syncthreads();
        #pragma unroll
        for (int t = 0; t < 2; ++t) {
            int c = t * 256 + tid;
            int m = c >> 2, kb = c & 3;
            async16(&A[(size_t)(m0 + m) * K + k0 + kb * 8], &As[c * 8]);
            async16(&B[(size_t)(n0 + m) * K + k0 + kb * 8], &Bs[c * 8]);
        }
        __syncthreads();
        bf16x8 af[4], bfr[4];
        #pragma unroll
        for (int i = 0; i < 4; ++i) {
            af[i]  = *reinterpret_cast<const bf16x8*>(&As[(wr * 64 + i * 16 + l16) * BK + quad * 8]);
            bfr[i] = *reinterpret_cast<const bf16x8*>(&Bs[(wc * 64 + i * 16 + l16) * BK + quad * 8]);
        }
        #pragma unroll
        for (int i = 0; i < 4; ++i)
            #pragma unroll
            for (int j = 0; j < 4; ++j)
                acc[i][j] = __builtin_amdgcn_mfma_f32_16x16x32_bf16(af[i], bfr[j], acc[i][j], 0, 0, 0);
    }

    #pragma unroll
    for (int j = 0; j < 4; ++j) {
        int n = n0 + wc * 64 + j * 16 + l16;
        float bv = bias[n];
        #pragma unroll
        for (int i = 0; i < 4; ++i) {
            #pragma unroll
            for (int r = 0; r < 4; ++r) {
                int m = m0 + wr * 64 + i * 16 + quad * 4 + r;
                out[(size_t)m * 1024 + n] = acc[i][j][r] + bv;
            }
        }
    }
}

// ---------------------------------------------------------------------------
extern "C" void kernel_launch(void* const* d_in, const int* in_sizes, int n_in,
                              void* d_out, int out_size, void* d_ws, size_t ws_size,
                              hipStream_t stream)
{
    const float* query = (const float*)d_in[0];   // [2048][2][1024]
    const float* wqkv  = (const float*)d_in[1];   // [3072][1024]
    const float* bqkv  = (const float*)d_in[2];   // [3072]
    const float* wout  = (const float*)d_in[3];   // [1024][1024]
    const float* bout  = (const float*)d_in[4];   // [1024]
    float* out = (float*)d_out;                   // [4096*1024] attn ++ [2*2048*2048] avg

    char* ws = (char*)d_ws;
    const size_t E_Q   = (size_t)M1 * EMB;        // 4M
    const size_t E_W   = (size_t)3 * EMB * EMB;   // 3M
    const size_t E_WO  = (size_t)EMB * EMB;       // 1M
    const size_t E_QKV = (size_t)BHN * T_LEN * HD;// 4M

    unsigned short* queryb = (unsigned short*)ws;   // 8 MB (reused as AO16 later)
    unsigned short* wqkvb  = queryb + E_Q;          // 6 MB (dead after qkv)
    unsigned short* woutb  = wqkvb + E_W;           // 2 MB (live till end)
    unsigned short* Q16    = woutb + E_WO;          // 8 MB
    unsigned short* K16    = Q16 + E_QKV;           // 8 MB
    unsigned short* Vt16   = K16 + E_QKV;           // 8 MB
    unsigned short* Opart  = Vt16 + E_QKV;          // 16 MB (2 x bf16 partial O)
    float* Lpart = (float*)(Opart + KSPLIT * E_Q);  // 0.5 MB
    float* Lrec  = Lpart + (size_t)KSPLIT * BHN * T_LEN;  // 0.25 MB
    unsigned short* AO16 = queryb;                  // alias: dead after qkv
    const size_t need = (E_Q + E_W + E_WO + 3 * E_QKV + KSPLIT * E_Q) * 2
                      + (KSPLIT + 1) * (size_t)BHN * T_LEN * 4;
    if (ws_size < need) return;

    cvt_bf16_kernel<<<(int)(E_Q / 8 / 256), 256, 0, stream>>>(query, queryb, (int)(E_Q / 8));
    cvt_bf16_kernel<<<(int)(E_W / 8 / 256), 256, 0, stream>>>(wqkv, wqkvb, (int)(E_W / 8));
    cvt_bf16_kernel<<<(int)(E_WO / 8 / 256), 256, 0, stream>>>(wout, woutb, (int)(E_WO / 8));

    qkv_mfma_kernel<<<dim3(M1 / 128, 3072 / 128), 256, 0, stream>>>(queryb, wqkvb, bqkv, Q16, K16, Vt16);
    flash_mfma_kernel<<<dim3(T_LEN / 128, BHN, KSPLIT), 256, 0, stream>>>(Q16, K16, Vt16, Opart, Lpart);
    combine_kernel<<<(int)(E_Q / 8 / 256), 256, 0, stream>>>(Opart, Lpart, AO16, Lrec);
    avg_mfma_kernel<<<dim3(T_LEN / 64, T_LEN / 64, BSZ), 256, 0, stream>>>(Q16, K16, Lrec, out + (size_t)M1 * EMB);
    out_mfma_kernel<<<dim3(M1 / 128, 1024 / 128), 256, 0, stream>>>(AO16, woutb, bout, out);
}